// Round 1
// 2279.098 us; speedup vs baseline: 1.6749x; 1.6749x over previous
//
#include <hip/hip_runtime.h>
#include <cstddef>

// SchNet fwd energy + force bwd, MI355X. Round 13: filter weights pre-converted
// to bf16 once per launch (4 layouts in workspace); MFMA B-fragments read
// directly from L1/L2-resident global (no per-block W2 staging); P-phase
// (rbf@W1) and GEMM3 (tbar@W1^T) moved from scalar VALU to MFMA. LDS 61->~22KB.

#define FD     128
#define NRBF   20
#define CUTF   5.0f
#define PI_F   3.14159265358979f
#define TF     32
#define TB     32
#define PW     136    // u16 pitch for sP/sWf
#define WLSZ   40960  // u16 per layer in weight workspace

typedef unsigned short u16;
typedef unsigned int   u32;
typedef __attribute__((ext_vector_type(8))) short bf16x8;
typedef __attribute__((ext_vector_type(4))) float f32x4;

__device__ __forceinline__ float u16f(u16 x){ union{u32 i; float f;} v; v.i=((u32)x)<<16; return v.f; }
__device__ __forceinline__ u16 f16r(float f){ union{float f; u32 i;} v; v.f=f; u32 r=v.i+0x7fffu+((v.i>>16)&1u); return (u16)(r>>16); }
__device__ __forceinline__ float sspf(float x){ return fmaxf(x,0.f)+log1pf(expf(-fabsf(x)))-0.6931471805599453f; }
__device__ __forceinline__ float sigf(float x){ return 1.f/(1.f+expf(-x)); }
__device__ __forceinline__ float fcutf(float d){ return (d < CUTF) ? 0.5f*(cosf(PI_F*d/CUTF)+1.f) : 0.f; }

__global__ __launch_bounds__(256) void k_zero(float* __restrict__ p, int n){
  int i = blockIdx.x*256 + threadIdx.x;
  if(i < n) p[i] = 0.f;
}

__global__ __launch_bounds__(256) void k_embed(const float* __restrict__ emb, const int* __restrict__ Z,
                                               float* __restrict__ X0, int n){
  int idx = blockIdx.x*256 + threadIdx.x;
  if(idx >= n) return;
  int a = idx >> 7, f = idx & 127;
  X0[idx] = emb[Z[a]*FD + f];
}

__global__ __launch_bounds__(256) void k_edge_geom(const float* __restrict__ pos,
    const int* __restrict__ Ii, const int* __restrict__ Ij,
    float* __restrict__ De, float* __restrict__ DBe, int E){
  int e = blockIdx.x*256 + threadIdx.x;
  if(e >= E) return;
  int i = Ii[e], j = Ij[e];
  float dx = pos[j*3+0]-pos[i*3+0];
  float dy = pos[j*3+1]-pos[i*3+1];
  float dz = pos[j*3+2]-pos[i*3+2];
  De[e] = sqrtf(dx*dx+dy*dy+dz*dz + 1e-12f);
  DBe[e] = 0.f;
}

__global__ __launch_bounds__(256) void k_compact(const float* __restrict__ De,
    int* __restrict__ EA, int* __restrict__ cnt, int E){
  int e = blockIdx.x*256 + threadIdx.x;
  if(e >= E) return;
  if(De[e] < CUTF){
    int p = atomicAdd(cnt, 1);
    EA[p] = e;
  }
}

// Per-layer bf16 weight pre-conversion (once per launch).
// Layout per layer l (u16 units), base = l*WLSZ:
//   +0     W1t [c=128][k=32]  (k>=20 zero)   -- B of P-phase MFMA
//   +4096  W1b [k=32][c=128]  (k>=20 zero)   -- B of GEMM3 MFMA
//   +8192  W2r [c=128][f=128] row-major      -- B of GEMM2 MFMA
//   +24576 W2t [f=128][c=128]                -- B of GEMM1 MFMA
__global__ __launch_bounds__(256) void k_prep(const float* __restrict__ fW1,
    const float* __restrict__ fW2, u16* __restrict__ WB){
  int idx = blockIdx.x*256 + threadIdx.x;
  if(idx >= 3*WLSZ) return;
  int l = idx / WLSZ, r = idx - l*WLSZ;
  const float* W1 = fW1 + l*2560;
  const float* W2 = fW2 + l*16384;
  u16* out = WB + l*WLSZ;
  if(r < 4096){
    int c = r >> 5, k = r & 31;
    out[r] = (k < NRBF) ? f16r(W1[k*128 + c]) : (u16)0;
  } else if(r < 8192){
    int rr = r - 4096;
    int k = rr >> 7, c = rr & 127;
    out[r] = (k < NRBF) ? f16r(W1[k*128 + c]) : (u16)0;
  } else if(r < 24576){
    out[r] = f16r(W2[r - 8192]);
  } else {
    int rr = r - 24576;
    int f = rr >> 7, c = rr & 127;
    out[r] = f16r(W2[c*128 + f]);
  }
}

// dense GEMM (unchanged, verified)
__global__ __launch_bounds__(256) void k_gemm32(const float* __restrict__ A, const float* __restrict__ B,
    const float* __restrict__ bias, const float* __restrict__ res,
    const float* __restrict__ mul, float* __restrict__ out1, float* __restrict__ out2,
    int transB, int act, int Nr){
  __shared__ float As[64*132];
  const int tid = threadIdx.x;
  const int rb = blockIdx.x * 64;
  for(int q=0;q<8;q++){
    int e = q*256 + tid;
    int r = e >> 5, c = (e & 31) * 4;
    int rr = rb + r; if(rr >= Nr) rr = Nr-1;
    *(float4*)&As[r*132 + c] = *(const float4*)(A + (size_t)rr*FD + c);
  }
  __syncthreads();
  const int r0 = (tid >> 4) * 4;
  const int f0 = (tid & 15) * 8;
  float acc[4][8] = {};
  if(!transB){
    for(int k=0;k<128;k++){
      float a[4] = {As[(r0+0)*132+k], As[(r0+1)*132+k], As[(r0+2)*132+k], As[(r0+3)*132+k]};
      float4 b0 = *(const float4*)(B + k*FD + f0);
      float4 b1 = *(const float4*)(B + k*FD + f0 + 4);
      float b[8] = {b0.x,b0.y,b0.z,b0.w,b1.x,b1.y,b1.z,b1.w};
      #pragma unroll
      for(int i=0;i<4;i++)
        #pragma unroll
        for(int j=0;j<8;j++) acc[i][j] += a[i]*b[j];
    }
  } else {
    for(int k=0;k<128;k++){
      float a[4] = {As[(r0+0)*132+k], As[(r0+1)*132+k], As[(r0+2)*132+k], As[(r0+3)*132+k]};
      float b[8];
      #pragma unroll
      for(int j=0;j<8;j++) b[j] = B[(size_t)(f0+j)*FD + k];
      #pragma unroll
      for(int i=0;i<4;i++)
        #pragma unroll
        for(int j=0;j<8;j++) acc[i][j] += a[i]*b[j];
    }
  }
  float bv[8];
  #pragma unroll
  for(int j=0;j<8;j++) bv[j] = bias ? bias[f0+j] : 0.f;
  #pragma unroll
  for(int rr=0;rr<4;rr++){
    int row = rb + r0 + rr;
    if(row >= Nr) break;
    size_t base = (size_t)row*FD + f0;
    float y[8];
    #pragma unroll
    for(int j=0;j<8;j++) y[j] = acc[rr][j] + bv[j];
    if(res){
      float4 r1 = *(const float4*)(res+base);
      float4 r2 = *(const float4*)(res+base+4);
      y[0]+=r1.x; y[1]+=r1.y; y[2]+=r1.z; y[3]+=r1.w;
      y[4]+=r2.x; y[5]+=r2.y; y[6]+=r2.z; y[7]+=r2.w;
    }
    if(mul){
      float4 m1 = *(const float4*)(mul+base);
      float4 m2 = *(const float4*)(mul+base+4);
      y[0]*=m1.x; y[1]*=m1.y; y[2]*=m1.z; y[3]*=m1.w;
      y[4]*=m2.x; y[5]*=m2.y; y[6]*=m2.z; y[7]*=m2.w;
    }
    if(act){
      *(float4*)(out1+base)   = make_float4(sspf(y[0]),sspf(y[1]),sspf(y[2]),sspf(y[3]));
      *(float4*)(out1+base+4) = make_float4(sspf(y[4]),sspf(y[5]),sspf(y[6]),sspf(y[7]));
      *(float4*)(out2+base)   = make_float4(sigf(y[0]),sigf(y[1]),sigf(y[2]),sigf(y[3]));
      *(float4*)(out2+base+4) = make_float4(sigf(y[4]),sigf(y[5]),sigf(y[6]),sigf(y[7]));
    } else {
      *(float4*)(out1+base)   = make_float4(y[0],y[1],y[2],y[3]);
      *(float4*)(out1+base+4) = make_float4(y[4],y[5],y[6],y[7]);
    }
  }
}

// ---- Edge forward v6: MFMA P-phase, global-bf16 B-fragments ----
__global__ __launch_bounds__(256) void k_edge_fwd6(
    const float* __restrict__ h,
    const int* __restrict__ Ii, const int* __restrict__ Ij,
    const float* __restrict__ De,
    const int* __restrict__ EA, const int* __restrict__ cnt,
    const u16* __restrict__ W1t, const float* __restrict__ b1,
    const u16* __restrict__ W2t, const float* __restrict__ b2,
    float* __restrict__ agg){
  __shared__ u16 srbfb[TF*32];   // rbf bf16, K-padded to 32
  __shared__ u16 sP [TF*PW];     // P [e][c]
  __shared__ u16 sWf[TF*PW];     // Wf [e][f]
  __shared__ int sI[TF], sJ[TF];
  __shared__ float sFc[TF], sDd[TF];
  const int tid = threadIdx.x;
  const int C = *cnt;
  const int base = blockIdx.x*TF;
  if(base >= C) return;
  if(tid < TF){
    int idx = base + tid;
    if(idx < C){
      int e = EA[idx];
      sI[tid]=Ii[e]; sJ[tid]=Ij[e];
      float d = De[e];
      sFc[tid]=fcutf(d); sDd[tid]=d;
    } else { sI[tid]=0; sJ[tid]=0; sFc[tid]=0.f; sDd[tid]=1.f; }
  }
  __syncthreads();
  const float step = CUTF/19.0f;
  const float coef = -0.5f/(step*step);
  for(int idx=tid; idx<TF*32; idx+=256){
    int t = idx >> 5, k = idx & 31;
    float x = sDd[t] - step*(float)k;
    srbfb[idx] = (k < NRBF) ? f16r(expf(coef*x*x)) : (u16)0;
  }
  __syncthreads();
  const int w = tid >> 6, lane = tid & 63;
  const int quad = lane >> 4, l16 = lane & 15;
  { // P = ssp(rbf @ W1 + b1) via MFMA (K=32, single step)
    f32x4 acc[2][2];
    #pragma unroll
    for(int m=0;m<2;m++){ acc[m][0]=(f32x4){0,0,0,0}; acc[m][1]=(f32x4){0,0,0,0}; }
    bf16x8 a[2], b[2];
    #pragma unroll
    for(int m=0;m<2;m++)
      a[m] = *(const bf16x8*)&srbfb[(m*16+l16)*32 + quad*8];
    #pragma unroll
    for(int p=0;p<2;p++)
      b[p] = *(const bf16x8*)(W1t + ((2*w+p)*16+l16)*32 + quad*8);
    #pragma unroll
    for(int m=0;m<2;m++)
      #pragma unroll
      for(int p=0;p<2;p++)
        acc[m][p] = __builtin_amdgcn_mfma_f32_16x16x32_bf16(a[m], b[p], acc[m][p], 0,0,0);
    #pragma unroll
    for(int m=0;m<2;m++)
      #pragma unroll
      for(int p=0;p<2;p++){
        const int c = (2*w+p)*16 + l16;
        float bb = b1[c];
        #pragma unroll
        for(int r=0;r<4;r++)
          sP[(m*16+quad*4+r)*PW + c] = f16r(sspf(acc[m][p][r] + bb));
      }
  }
  __syncthreads();
  { // GEMM1 MFMA: Wf = P@W2 + b2; B-fragments from global W2t [f][c]
    f32x4 acc[2][2];
    #pragma unroll
    for(int m=0;m<2;m++){ acc[m][0]=(f32x4){0,0,0,0}; acc[m][1]=(f32x4){0,0,0,0}; }
    #pragma unroll
    for(int ks=0;ks<4;ks++){
      bf16x8 a[2], b[2];
      #pragma unroll
      for(int m=0;m<2;m++)
        a[m] = *(const bf16x8*)&sP[(m*16+l16)*PW + ks*32 + quad*8];
      #pragma unroll
      for(int p=0;p<2;p++)
        b[p] = *(const bf16x8*)(W2t + ((2*w+p)*16+l16)*128 + ks*32 + quad*8);
      #pragma unroll
      for(int m=0;m<2;m++)
        #pragma unroll
        for(int p=0;p<2;p++)
          acc[m][p] = __builtin_amdgcn_mfma_f32_16x16x32_bf16(a[m], b[p], acc[m][p], 0,0,0);
    }
    #pragma unroll
    for(int m=0;m<2;m++)
      #pragma unroll
      for(int p=0;p<2;p++){
        const int f = (2*w+p)*16 + l16;
        float bb = b2[f];
        #pragma unroll
        for(int r=0;r<4;r++)
          sWf[(m*16+quad*4+r)*PW + f] = f16r(acc[m][p][r] + bb);
      }
  }
  __syncthreads();
  { // coalesced scatter
    for(int s=0;s<8;s++){
      int tt = w*8 + s;
      if(base + tt >= C) continue;
      int i = sI[tt], j = sJ[tt];
      float fc = sFc[tt];
      float h0 = h[(size_t)j*FD + lane];
      float h1 = h[(size_t)j*FD + lane + 64];
      float w0 = u16f(sWf[tt*PW + lane]);
      float w1 = u16f(sWf[tt*PW + lane + 64]);
      atomicAdd(&agg[(size_t)i*FD + lane],      h0*w0*fc);
      atomicAdd(&agg[(size_t)i*FD + lane + 64], h1*w1*fc);
    }
  }
}

// ---- Edge backward v6: MFMA P-phase + MFMA GEMM3, global-bf16 B-fragments ----
__global__ __launch_bounds__(256) void k_edge_bwd6(
    const float* __restrict__ h, const float* __restrict__ AB,
    const int* __restrict__ Ii, const int* __restrict__ Ij,
    const float* __restrict__ De,
    const int* __restrict__ EA, const int* __restrict__ cnt,
    const u16* __restrict__ W1t, const float* __restrict__ b1,
    const u16* __restrict__ W1b, const u16* __restrict__ W2r,
    const u16* __restrict__ W2t, const float* __restrict__ b2,
    float* __restrict__ DBe, float* __restrict__ HB){
  __shared__ u16 srbfb[TB*32];    // rbf bf16, K-padded
  __shared__ float srbf[TB*NRBF]; // rbf f32 (dbar epilogue)
  __shared__ u16 sP [TB*PW];      // P [e][c] (kept whole kernel)
  __shared__ u16 sWf[TB*PW];      // Wf -> Wbar -> tbar
  __shared__ float sdb[TB*2];     // dbar partials per n-tile
  __shared__ int sI[TB], sJ[TB], sE[TB];
  __shared__ float sFc[TB], sDd[TB], sfb[TB];
  const int tid = threadIdx.x;
  const int C = *cnt;
  const int base = blockIdx.x*TB;
  if(base >= C) return;
  if(tid < TB){
    int idx = base + tid;
    if(idx < C){
      int e = EA[idx];
      sE[tid]=e; sI[tid]=Ii[e]; sJ[tid]=Ij[e];
      float d = De[e];
      sFc[tid]=fcutf(d); sDd[tid]=d;
    } else { sE[tid]=0; sI[tid]=0; sJ[tid]=0; sFc[tid]=0.f; sDd[tid]=1.f; }
  }
  __syncthreads();
  const float step = CUTF/19.0f;
  const float coef = -0.5f/(step*step);
  for(int idx=tid; idx<TB*32; idx+=256){
    int t = idx >> 5, k = idx & 31;
    float x = sDd[t] - step*(float)k;
    if(k < NRBF){
      float v = expf(coef*x*x);
      srbf[t*NRBF + k] = v;
      srbfb[idx] = f16r(v);
    } else srbfb[idx] = (u16)0;
  }
  __syncthreads();
  const int w = tid >> 6, lane = tid & 63;
  const int quad = lane >> 4, l16 = lane & 15;
  { // P = ssp(rbf @ W1 + b1) via MFMA (sigma recovered later from P)
    f32x4 acc[2][2];
    #pragma unroll
    for(int m=0;m<2;m++){ acc[m][0]=(f32x4){0,0,0,0}; acc[m][1]=(f32x4){0,0,0,0}; }
    bf16x8 a[2], b[2];
    #pragma unroll
    for(int m=0;m<2;m++)
      a[m] = *(const bf16x8*)&srbfb[(m*16+l16)*32 + quad*8];
    #pragma unroll
    for(int p=0;p<2;p++)
      b[p] = *(const bf16x8*)(W1t + ((2*w+p)*16+l16)*32 + quad*8);
    #pragma unroll
    for(int m=0;m<2;m++)
      #pragma unroll
      for(int p=0;p<2;p++)
        acc[m][p] = __builtin_amdgcn_mfma_f32_16x16x32_bf16(a[m], b[p], acc[m][p], 0,0,0);
    #pragma unroll
    for(int m=0;m<2;m++)
      #pragma unroll
      for(int p=0;p<2;p++){
        const int c = (2*w+p)*16 + l16;
        float bb = b1[c];
        #pragma unroll
        for(int r=0;r<4;r++)
          sP[(m*16+quad*4+r)*PW + c] = f16r(sspf(acc[m][p][r] + bb));
      }
  }
  __syncthreads();
  { // GEMM1 MFMA: Wf = P@W2 + b2; B from global W2t [f][c]
    f32x4 acc[2][2];
    #pragma unroll
    for(int m=0;m<2;m++){ acc[m][0]=(f32x4){0,0,0,0}; acc[m][1]=(f32x4){0,0,0,0}; }
    #pragma unroll
    for(int ks=0;ks<4;ks++){
      bf16x8 a[2], b[2];
      #pragma unroll
      for(int m=0;m<2;m++)
        a[m] = *(const bf16x8*)&sP[(m*16+l16)*PW + ks*32 + quad*8];
      #pragma unroll
      for(int p=0;p<2;p++)
        b[p] = *(const bf16x8*)(W2t + ((2*w+p)*16+l16)*128 + ks*32 + quad*8);
      #pragma unroll
      for(int m=0;m<2;m++)
        #pragma unroll
        for(int p=0;p<2;p++)
          acc[m][p] = __builtin_amdgcn_mfma_f32_16x16x32_bf16(a[m], b[p], acc[m][p], 0,0,0);
    }
    #pragma unroll
    for(int m=0;m<2;m++)
      #pragma unroll
      for(int p=0;p<2;p++){
        const int f = (2*w+p)*16 + l16;
        float bb = b2[f];
        #pragma unroll
        for(int r=0;r<4;r++)
          sWf[(m*16+quad*4+r)*PW + f] = f16r(acc[m][p][r] + bb);
      }
  }
  __syncthreads();
  { // scatter + Wbar (in-place per-element into sWf) + fbar
    for(int s=0;s<8;s++){
      int tt = w*8 + s;
      if(base + tt >= C) continue;
      int i = sI[tt], j = sJ[tt];
      float fc = sFc[tt];
      float a0 = AB[(size_t)i*FD + lane];
      float a1 = AB[(size_t)i*FD + lane + 64];
      float h0 = h [(size_t)j*FD + lane];
      float h1 = h [(size_t)j*FD + lane + 64];
      float w0 = u16f(sWf[tt*PW + lane]);
      float w1 = u16f(sWf[tt*PW + lane + 64]);
      atomicAdd(&HB[(size_t)j*FD + lane],      a0*w0*fc);
      atomicAdd(&HB[(size_t)j*FD + lane + 64], a1*w1*fc);
      float g0 = a0*h0, g1 = a1*h1;
      sWf[tt*PW + lane]      = f16r(g0*fc);
      sWf[tt*PW + lane + 64] = f16r(g1*fc);
      float pf = g0*w0 + g1*w1;
      #pragma unroll
      for(int d2=1; d2<64; d2<<=1) pf += __shfl_xor(pf, d2);
      if(lane == 0) sfb[tt] = pf;
    }
  }
  __syncthreads();
  float tb[2][2][4];
  { // GEMM2 MFMA: Pbar = Wbar@W2^T; B from global W2r [c][f]; sigma-trick into regs
    f32x4 acc[2][2];
    #pragma unroll
    for(int m=0;m<2;m++){ acc[m][0]=(f32x4){0,0,0,0}; acc[m][1]=(f32x4){0,0,0,0}; }
    #pragma unroll
    for(int ks=0;ks<4;ks++){
      bf16x8 a[2], b[2];
      #pragma unroll
      for(int m=0;m<2;m++)
        a[m] = *(const bf16x8*)&sWf[(m*16+l16)*PW + ks*32 + quad*8];
      #pragma unroll
      for(int p=0;p<2;p++)
        b[p] = *(const bf16x8*)(W2r + ((2*w+p)*16+l16)*128 + ks*32 + quad*8);
      #pragma unroll
      for(int m=0;m<2;m++)
        #pragma unroll
        for(int p=0;p<2;p++)
          acc[m][p] = __builtin_amdgcn_mfma_f32_16x16x32_bf16(a[m], b[p], acc[m][p], 0,0,0);
    }
    #pragma unroll
    for(int m=0;m<2;m++)
      #pragma unroll
      for(int p=0;p<2;p++){
        const int c = (2*w+p)*16 + l16;
        #pragma unroll
        for(int r=0;r<4;r++){
          float Pv = u16f(sP[(m*16+quad*4+r)*PW + c]);
          float sig = 1.0f - 0.5f*expf(-Pv);
          tb[m][p][r] = acc[m][p][r] * sig;
        }
      }
  }
  __syncthreads();   // all Wbar fragment reads complete
  { // write tbar into sWf
    #pragma unroll
    for(int m=0;m<2;m++)
      #pragma unroll
      for(int p=0;p<2;p++){
        const int c = (2*w+p)*16 + l16;
        #pragma unroll
        for(int r=0;r<4;r++)
          sWf[(m*16+quad*4+r)*PW + c] = f16r(tb[m][p][r]);
      }
  }
  __syncthreads();
  { // GEMM3 MFMA: rbar = tbar@W1^T (B from global W1b [k32][c]); dbar partials
    const int m3 = w >> 1, p3 = w & 1;   // wave -> (m-tile, n-tile)
    f32x4 acc = (f32x4){0,0,0,0};
    #pragma unroll
    for(int ks=0;ks<4;ks++){
      bf16x8 a = *(const bf16x8*)&sWf[(m3*16+l16)*PW + ks*32 + quad*8];
      bf16x8 b = *(const bf16x8*)(W1b + (p3*16+l16)*128 + ks*32 + quad*8);
      acc = __builtin_amdgcn_mfma_f32_16x16x32_bf16(a, b, acc, 0,0,0);
    }
    const int kr = p3*16 + l16;
    float s0[4];
    #pragma unroll
    for(int r=0;r<4;r++){
      int e = m3*16 + quad*4 + r;
      float v = 0.f;
      if(kr < NRBF){
        float x = sDd[e] - step*(float)kr;
        v = acc[r] * srbf[e*NRBF + kr] * (2.f*coef*x);
      }
      s0[r] = v;
    }
    #pragma unroll
    for(int d2=1; d2<16; d2<<=1){
      #pragma unroll
      for(int r=0;r<4;r++) s0[r] += __shfl_xor(s0[r], d2);
    }
    if(l16 == 0){
      #pragma unroll
      for(int r=0;r<4;r++) sdb[(m3*16+quad*4+r)*2 + p3] = s0[r];
    }
  }
  __syncthreads();
  if(tid < TB){
    if(base + tid < C){
      const float d = sDd[tid];
      float dfc = (d < CUTF) ? (-0.5f*(PI_F/CUTF)*sinf(PI_F*d/CUTF)) : 0.f;
      DBe[sE[tid]] += sdb[tid*2+0] + sdb[tid*2+1] + sfb[tid]*dfc;
    }
  }
}

// fused atomwise head + head-backward (unchanged, verified)
__global__ __launch_bounds__(256) void k_head(const float* __restrict__ X3,
    const float* __restrict__ aW1, const float* __restrict__ ab1,
    const float* __restrict__ aW2, const float* __restrict__ ab2,
    const int* __restrict__ mol, float* __restrict__ Emol, float* __restrict__ XB, int N){
  __shared__ float sx[64*129];
  __shared__ float sg[64*65];
  const int tid = threadIdx.x;
  const int base = blockIdx.x*64;
  for(int q=0;q<8;q++){
    int ee = q*256 + tid;
    int r = ee >> 5, c = (ee & 31)*4;
    int row = base + r; if(row >= N) row = N-1;
    float4 v = *(const float4*)(X3 + (size_t)row*FD + c);
    sx[r*129 + c+0] = v.x; sx[r*129 + c+1] = v.y;
    sx[r*129 + c+2] = v.z; sx[r*129 + c+3] = v.w;
  }
  __syncthreads();
  {
    const int a = tid >> 2, q = tid & 3;
    float pe = 0.f;
    for(int cc=0; cc<16; cc++){
      int c = q*16 + cc;
      float u = ab1[c];
      for(int f=0; f<128; f++) u += sx[a*129 + f]*aW1[f*64 + c];
      pe += sspf(u)*aW2[c];
      sg[a*65 + c] = sigf(u)*aW2[c];
    }
    pe += __shfl_xor(pe, 1);
    pe += __shfl_xor(pe, 2);
    if(q == 0 && base + a < N) atomicAdd(&Emol[mol[base + a]], pe + ab2[0]);
  }
  __syncthreads();
  {
    const int f = tid & 127, g2 = tid >> 7;
    float acc[32];
    #pragma unroll
    for(int q=0;q<32;q++) acc[q]=0.f;
    for(int c=0;c<64;c++){
      float w = aW1[f*64 + c];
      #pragma unroll
      for(int q=0;q<32;q++) acc[q] += sg[(g2*32+q)*65 + c]*w;
    }
    #pragma unroll
    for(int q=0;q<32;q++){
      int row = base + g2*32 + q;
      if(row < N) XB[(size_t)row*FD + f] = acc[q];
    }
  }
}

__global__ __launch_bounds__(256) void k_grad(const float* __restrict__ pos,
    const int* __restrict__ Ii, const int* __restrict__ Ij,
    const float* __restrict__ De, const float* __restrict__ DBe,
    const int* __restrict__ EA, const int* __restrict__ cnt,
    float* __restrict__ G){
  int idx = blockIdx.x*256 + threadIdx.x;
  if(idx >= *cnt) return;
  int e = EA[idx];
  float s = DBe[e] / De[e];
  int i = Ii[e], j = Ij[e];
  float dx = s*(pos[i*3+0]-pos[j*3+0]);
  float dy = s*(pos[i*3+1]-pos[j*3+1]);
  float dz = s*(pos[i*3+2]-pos[j*3+2]);
  atomicAdd(&G[i*3+0], dx); atomicAdd(&G[i*3+1], dy); atomicAdd(&G[i*3+2], dz);
  atomicAdd(&G[j*3+0], -dx); atomicAdd(&G[j*3+1], -dy); atomicAdd(&G[j*3+2], -dz);
}

__global__ __launch_bounds__(256) void k_norm(const float* __restrict__ G,
    const int* __restrict__ mol, u32* __restrict__ maxnU, int N){
  int n = blockIdx.x*256 + threadIdx.x;
  if(n >= N) return;
  float ax = G[n*3], ay = G[n*3+1], az = G[n*3+2];
  float nrm = sqrtf(ax*ax+ay*ay+az*az);
  atomicMax(&maxnU[mol[n]], __float_as_uint(nrm));
}

__global__ __launch_bounds__(256) void k_apply(const float* __restrict__ G,
    const int* __restrict__ mol, const u32* __restrict__ maxnU,
    float* __restrict__ outA, int N){
  int n = blockIdx.x*256 + threadIdx.x;
  if(n >= N) return;
  float mx = __uint_as_float(maxnU[mol[n]]);
  float coefc = fminf(1.0f/fmaxf(mx, 1e-8f), 1.0f);
  outA[n*3+0] = -G[n*3+0]*coefc;
  outA[n*3+1] = -G[n*3+1]*coefc;
  outA[n*3+2] = -G[n*3+2]*coefc;
}

extern "C" void kernel_launch(void* const* d_in, const int* in_sizes, int n_in,
                              void* d_out, int out_size, void* d_ws, size_t ws_size,
                              hipStream_t stream) {
  (void)n_in;
  const float* pos  = (const float*)d_in[0];
  const float* emb  = (const float*)d_in[1];
  const float* in2f = (const float*)d_in[2];
  const float* fW1  = (const float*)d_in[3];
  const float* fb1  = (const float*)d_in[4];
  const float* fW2  = (const float*)d_in[5];
  const float* fb2  = (const float*)d_in[6];
  const float* oW1  = (const float*)d_in[7];
  const float* ob1  = (const float*)d_in[8];
  const float* oW2  = (const float*)d_in[9];
  const float* ob2  = (const float*)d_in[10];
  const float* aW1  = (const float*)d_in[11];
  const float* ab1  = (const float*)d_in[12];
  const float* aW2  = (const float*)d_in[13];
  const float* ab2  = (const float*)d_in[14];
  const int*   Z    = (const int*)d_in[15];
  const int*   Ii   = (const int*)d_in[16];
  const int*   Ij   = (const int*)d_in[17];
  const int*   mol  = (const int*)d_in[18];
  const int N = in_sizes[15];
  const int E = in_sizes[16];
  const int M = out_size - N*3;
  const size_t NFE = (size_t)N*FD;
  float* outF = (float*)d_out;
  float* outE = outF + (size_t)N*3;
  float* ws = (float*)d_ws;
  if(ws_size < (11*NFE + 3*(size_t)E + 16 + 3*(WLSZ/2) + 64)*4) return;

  float* X0  = ws;
  float* SV0 = ws + 4*NFE;
  float* H   = ws + 7*NFE;
  float* AGG = ws + 8*NFE;
  float* XB  = ws + 9*NFE;
  float* HB  = ws + 10*NFE;
  float* De  = ws + 11*NFE;
  float* DBe = De + E;
  int*   EA  = (int*)(DBe + E);
  int*   cnt = EA + E;
  u16*   WB  = (u16*)(cnt + 16);   // 3*WLSZ u16, 16B-aligned
  float* G    = AGG;
  u32*  maxnU = (u32*)H;

  const int gN   = (int)((NFE + 255)/256);
  const int gE   = (E + 255)/256;
  const int gTF  = (E + TF-1)/TF;
  const int gTB  = (E + TB-1)/TB;
  const int gRow = (N + 63)/64;

  k_embed<<<gN,256,0,stream>>>(emb, Z, X0, (int)NFE);
  k_edge_geom<<<gE,256,0,stream>>>(pos, Ii, Ij, De, DBe, E);
  k_zero<<<1,256,0,stream>>>((float*)cnt, 1);
  k_compact<<<gE,256,0,stream>>>(De, EA, cnt, E);
  k_prep<<<(3*WLSZ+255)/256,256,0,stream>>>(fW1, fW2, WB);
  for(int l=0;l<3;l++){
    float* Xl  = X0 + (size_t)l*NFE;
    float* Xn  = X0 + (size_t)(l+1)*NFE;
    float* SVl = SV0 + (size_t)l*NFE;
    const u16* W1t = WB + l*WLSZ;
    const u16* W2t = W1t + 24576;
    k_gemm32<<<gRow,256,0,stream>>>(Xl, in2f + l*16384, nullptr, nullptr, nullptr, H, nullptr, 0, 0, N);
    k_zero<<<gN,256,0,stream>>>(AGG, (int)NFE);
    k_edge_fwd6<<<gTF,256,0,stream>>>(H, Ii, Ij, De, EA, cnt, W1t, fb1 + l*128, W2t, fb2 + l*128, AGG);
    k_gemm32<<<gRow,256,0,stream>>>(AGG, oW1 + l*16384, ob1 + l*128, nullptr, nullptr, H, SVl, 0, 1, N);
    k_gemm32<<<gRow,256,0,stream>>>(H, oW2 + l*16384, ob2 + l*128, Xl, nullptr, Xn, nullptr, 0, 0, N);
  }
  k_zero<<<(M+255)/256,256,0,stream>>>(outE, M);
  k_head<<<gRow,256,0,stream>>>(X0 + 3*NFE, aW1, ab1, aW2, ab2, mol, outE, XB, N);
  for(int l=2;l>=0;l--){
    float* Xl  = X0 + (size_t)l*NFE;
    float* SVl = SV0 + (size_t)l*NFE;
    const u16* W1t = WB + l*WLSZ;
    const u16* W1b = W1t + 4096;
    const u16* W2r = W1t + 8192;
    const u16* W2t = W1t + 24576;
    k_gemm32<<<gRow,256,0,stream>>>(XB, oW2 + l*16384, nullptr, nullptr, SVl, AGG, nullptr, 1, 0, N);
    k_gemm32<<<gRow,256,0,stream>>>(AGG, oW1 + l*16384, nullptr, nullptr, nullptr, AGG, nullptr, 1, 0, N);
    k_gemm32<<<gRow,256,0,stream>>>(Xl, in2f + l*16384, nullptr, nullptr, nullptr, H, nullptr, 0, 0, N);
    k_zero<<<gN,256,0,stream>>>(HB, (int)NFE);
    k_edge_bwd6<<<gTB,256,0,stream>>>(H, AGG, Ii, Ij, De, EA, cnt, W1t, fb1 + l*128, W1b, W2r, W2t, fb2 + l*128, DBe, HB);
    k_gemm32<<<gRow,256,0,stream>>>(HB, in2f + l*16384, nullptr, XB, nullptr, XB, nullptr, 1, 0, N);
  }
  k_zero<<<(N*3+255)/256,256,0,stream>>>(G, N*3);
  k_zero<<<(M+255)/256,256,0,stream>>>((float*)maxnU, M);
  k_grad<<<gE,256,0,stream>>>(pos, Ii, Ij, De, DBe, EA, cnt, G);
  k_norm<<<(N+255)/256,256,0,stream>>>(G, mol, maxnU, N);
  k_apply<<<(N+255)/256,256,0,stream>>>(G, mol, maxnU, outF, N);
}

// Round 2
// 2135.667 us; speedup vs baseline: 1.7874x; 1.0672x over previous
//
#include <hip/hip_runtime.h>
#include <cstddef>

// SchNet fwd energy + force bwd, MI355X. Round 14: fast hardware transcendentals
// (v_exp/v_log) for ssp/sigmoid/rbf (bf16-invisible error); k_gemm32 v2 with
// col-major LDS A (ds_read_b64), 32-row tiles for 2 blocks/CU; k_head phase-1
// loop interchange. Edge kernels keep R13 MFMA structure.

#define FD     128
#define NRBF   20
#define CUTF   5.0f
#define PI_F   3.14159265358979f
#define TF     32
#define TB     32
#define PW     136    // u16 pitch for sP/sWf
#define WLSZ   40960  // u16 per layer in weight workspace
#define GR     32     // k_gemm32 rows/block

typedef unsigned short u16;
typedef unsigned int   u32;
typedef __attribute__((ext_vector_type(8))) short bf16x8;
typedef __attribute__((ext_vector_type(4))) float f32x4;

__device__ __forceinline__ float u16f(u16 x){ union{u32 i; float f;} v; v.i=((u32)x)<<16; return v.f; }
__device__ __forceinline__ u16 f16r(float f){ union{float f; u32 i;} v; v.f=f; u32 r=v.i+0x7fffu+((v.i>>16)&1u); return (u16)(r>>16); }
// fast ssp / sigmoid via v_exp_f32/v_log_f32 (error ~2^-21 rel, invisible at bf16)
__device__ __forceinline__ float sspf(float x){
  return fmaxf(x,0.f) + __logf(1.f + __expf(-fabsf(x))) - 0.6931471805599453f;
}
__device__ __forceinline__ float sigf(float x){
  return __fdividef(1.f, 1.f + __expf(-x));
}
__device__ __forceinline__ float fcutf(float d){ return (d < CUTF) ? 0.5f*(cosf(PI_F*d/CUTF)+1.f) : 0.f; }

__global__ __launch_bounds__(256) void k_zero(float* __restrict__ p, int n){
  int i = blockIdx.x*256 + threadIdx.x;
  if(i < n) p[i] = 0.f;
}

__global__ __launch_bounds__(256) void k_embed(const float* __restrict__ emb, const int* __restrict__ Z,
                                               float* __restrict__ X0, int n){
  int idx = blockIdx.x*256 + threadIdx.x;
  if(idx >= n) return;
  int a = idx >> 7, f = idx & 127;
  X0[idx] = emb[Z[a]*FD + f];
}

__global__ __launch_bounds__(256) void k_edge_geom(const float* __restrict__ pos,
    const int* __restrict__ Ii, const int* __restrict__ Ij,
    float* __restrict__ De, float* __restrict__ DBe, int E){
  int e = blockIdx.x*256 + threadIdx.x;
  if(e >= E) return;
  int i = Ii[e], j = Ij[e];
  float dx = pos[j*3+0]-pos[i*3+0];
  float dy = pos[j*3+1]-pos[i*3+1];
  float dz = pos[j*3+2]-pos[i*3+2];
  De[e] = sqrtf(dx*dx+dy*dy+dz*dz + 1e-12f);
  DBe[e] = 0.f;
}

__global__ __launch_bounds__(256) void k_compact(const float* __restrict__ De,
    int* __restrict__ EA, int* __restrict__ cnt, int E){
  int e = blockIdx.x*256 + threadIdx.x;
  if(e >= E) return;
  if(De[e] < CUTF){
    int p = atomicAdd(cnt, 1);
    EA[p] = e;
  }
}

// Per-layer bf16 weight pre-conversion (once per launch).
__global__ __launch_bounds__(256) void k_prep(const float* __restrict__ fW1,
    const float* __restrict__ fW2, u16* __restrict__ WB){
  int idx = blockIdx.x*256 + threadIdx.x;
  if(idx >= 3*WLSZ) return;
  int l = idx / WLSZ, r = idx - l*WLSZ;
  const float* W1 = fW1 + l*2560;
  const float* W2 = fW2 + l*16384;
  u16* out = WB + l*WLSZ;
  if(r < 4096){
    int c = r >> 5, k = r & 31;
    out[r] = (k < NRBF) ? f16r(W1[k*128 + c]) : (u16)0;
  } else if(r < 8192){
    int rr = r - 4096;
    int k = rr >> 7, c = rr & 127;
    out[r] = (k < NRBF) ? f16r(W1[k*128 + c]) : (u16)0;
  } else if(r < 24576){
    out[r] = f16r(W2[r - 8192]);
  } else {
    int rr = r - 24576;
    int f = rr >> 7, c = rr & 127;
    out[r] = f16r(W2[c*128 + f]);
  }
}

// dense GEMM v2: col-major LDS A (ds_read_b64 fragments), 32-row tiles,
// 2 blocks/CU, 2x8 accumulator per thread.
__global__ __launch_bounds__(256) void k_gemm32(const float* __restrict__ A, const float* __restrict__ B,
    const float* __restrict__ bias, const float* __restrict__ res,
    const float* __restrict__ mul, float* __restrict__ out1, float* __restrict__ out2,
    int transB, int act, int Nr){
  __shared__ float As[128*34];   // [k][r], pitch 34
  const int tid = threadIdx.x;
  const int rb = blockIdx.x * GR;
  #pragma unroll
  for(int q=0;q<4;q++){
    int e = q*256 + tid;            // 0..1023
    int r = e >> 5, c4 = (e & 31)*4;
    int rr = rb + r; if(rr >= Nr) rr = Nr-1;
    float4 v = *(const float4*)(A + (size_t)rr*FD + c4);
    As[(c4+0)*34 + r] = v.x;
    As[(c4+1)*34 + r] = v.y;
    As[(c4+2)*34 + r] = v.z;
    As[(c4+3)*34 + r] = v.w;
  }
  __syncthreads();
  const int r0 = (tid >> 4)*2;
  const int f0 = (tid & 15)*8;
  float acc[2][8] = {};
  if(!transB){
    #pragma unroll 8
    for(int k=0;k<128;k++){
      float2 a = *(const float2*)&As[k*34 + r0];
      float4 b0 = *(const float4*)(B + k*FD + f0);
      float4 b1 = *(const float4*)(B + k*FD + f0 + 4);
      float b[8] = {b0.x,b0.y,b0.z,b0.w,b1.x,b1.y,b1.z,b1.w};
      #pragma unroll
      for(int j=0;j<8;j++){ acc[0][j] += a.x*b[j]; acc[1][j] += a.y*b[j]; }
    }
  } else {
    #pragma unroll 4
    for(int k=0;k<128;k++){
      float2 a = *(const float2*)&As[k*34 + r0];
      float b[8];
      #pragma unroll
      for(int j=0;j<8;j++) b[j] = B[(size_t)(f0+j)*FD + k];
      #pragma unroll
      for(int j=0;j<8;j++){ acc[0][j] += a.x*b[j]; acc[1][j] += a.y*b[j]; }
    }
  }
  float bv[8];
  #pragma unroll
  for(int j=0;j<8;j++) bv[j] = bias ? bias[f0+j] : 0.f;
  #pragma unroll
  for(int rr=0;rr<2;rr++){
    int row = rb + r0 + rr;
    if(row >= Nr) break;
    size_t base = (size_t)row*FD + f0;
    float y[8];
    #pragma unroll
    for(int j=0;j<8;j++) y[j] = acc[rr][j] + bv[j];
    if(res){
      float4 r1 = *(const float4*)(res+base);
      float4 r2 = *(const float4*)(res+base+4);
      y[0]+=r1.x; y[1]+=r1.y; y[2]+=r1.z; y[3]+=r1.w;
      y[4]+=r2.x; y[5]+=r2.y; y[6]+=r2.z; y[7]+=r2.w;
    }
    if(mul){
      float4 m1 = *(const float4*)(mul+base);
      float4 m2 = *(const float4*)(mul+base+4);
      y[0]*=m1.x; y[1]*=m1.y; y[2]*=m1.z; y[3]*=m1.w;
      y[4]*=m2.x; y[5]*=m2.y; y[6]*=m2.z; y[7]*=m2.w;
    }
    if(act){
      *(float4*)(out1+base)   = make_float4(sspf(y[0]),sspf(y[1]),sspf(y[2]),sspf(y[3]));
      *(float4*)(out1+base+4) = make_float4(sspf(y[4]),sspf(y[5]),sspf(y[6]),sspf(y[7]));
      *(float4*)(out2+base)   = make_float4(sigf(y[0]),sigf(y[1]),sigf(y[2]),sigf(y[3]));
      *(float4*)(out2+base+4) = make_float4(sigf(y[4]),sigf(y[5]),sigf(y[6]),sigf(y[7]));
    } else {
      *(float4*)(out1+base)   = make_float4(y[0],y[1],y[2],y[3]);
      *(float4*)(out1+base+4) = make_float4(y[4],y[5],y[6],y[7]);
    }
  }
}

// ---- Edge forward v6: MFMA P-phase, global-bf16 B-fragments ----
__global__ __launch_bounds__(256) void k_edge_fwd6(
    const float* __restrict__ h,
    const int* __restrict__ Ii, const int* __restrict__ Ij,
    const float* __restrict__ De,
    const int* __restrict__ EA, const int* __restrict__ cnt,
    const u16* __restrict__ W1t, const float* __restrict__ b1,
    const u16* __restrict__ W2t, const float* __restrict__ b2,
    float* __restrict__ agg){
  __shared__ u16 srbfb[TF*32];   // rbf bf16, K-padded to 32
  __shared__ u16 sP [TF*PW];     // P [e][c]
  __shared__ u16 sWf[TF*PW];     // Wf [e][f]
  __shared__ int sI[TF], sJ[TF];
  __shared__ float sFc[TF], sDd[TF];
  const int tid = threadIdx.x;
  const int C = *cnt;
  const int base = blockIdx.x*TF;
  if(base >= C) return;
  if(tid < TF){
    int idx = base + tid;
    if(idx < C){
      int e = EA[idx];
      sI[tid]=Ii[e]; sJ[tid]=Ij[e];
      float d = De[e];
      sFc[tid]=fcutf(d); sDd[tid]=d;
    } else { sI[tid]=0; sJ[tid]=0; sFc[tid]=0.f; sDd[tid]=1.f; }
  }
  __syncthreads();
  const float step = CUTF/19.0f;
  const float coef = -0.5f/(step*step);
  for(int idx=tid; idx<TF*32; idx+=256){
    int t = idx >> 5, k = idx & 31;
    float x = sDd[t] - step*(float)k;
    srbfb[idx] = (k < NRBF) ? f16r(__expf(coef*x*x)) : (u16)0;
  }
  __syncthreads();
  const int w = tid >> 6, lane = tid & 63;
  const int quad = lane >> 4, l16 = lane & 15;
  { // P = ssp(rbf @ W1 + b1) via MFMA (K=32, single step)
    f32x4 acc[2][2];
    #pragma unroll
    for(int m=0;m<2;m++){ acc[m][0]=(f32x4){0,0,0,0}; acc[m][1]=(f32x4){0,0,0,0}; }
    bf16x8 a[2], b[2];
    #pragma unroll
    for(int m=0;m<2;m++)
      a[m] = *(const bf16x8*)&srbfb[(m*16+l16)*32 + quad*8];
    #pragma unroll
    for(int p=0;p<2;p++)
      b[p] = *(const bf16x8*)(W1t + ((2*w+p)*16+l16)*32 + quad*8);
    #pragma unroll
    for(int m=0;m<2;m++)
      #pragma unroll
      for(int p=0;p<2;p++)
        acc[m][p] = __builtin_amdgcn_mfma_f32_16x16x32_bf16(a[m], b[p], acc[m][p], 0,0,0);
    #pragma unroll
    for(int m=0;m<2;m++)
      #pragma unroll
      for(int p=0;p<2;p++){
        const int c = (2*w+p)*16 + l16;
        float bb = b1[c];
        #pragma unroll
        for(int r=0;r<4;r++)
          sP[(m*16+quad*4+r)*PW + c] = f16r(sspf(acc[m][p][r] + bb));
      }
  }
  __syncthreads();
  { // GEMM1 MFMA: Wf = P@W2 + b2; B-fragments from global W2t [f][c]
    f32x4 acc[2][2];
    #pragma unroll
    for(int m=0;m<2;m++){ acc[m][0]=(f32x4){0,0,0,0}; acc[m][1]=(f32x4){0,0,0,0}; }
    #pragma unroll
    for(int ks=0;ks<4;ks++){
      bf16x8 a[2], b[2];
      #pragma unroll
      for(int m=0;m<2;m++)
        a[m] = *(const bf16x8*)&sP[(m*16+l16)*PW + ks*32 + quad*8];
      #pragma unroll
      for(int p=0;p<2;p++)
        b[p] = *(const bf16x8*)(W2t + ((2*w+p)*16+l16)*128 + ks*32 + quad*8);
      #pragma unroll
      for(int m=0;m<2;m++)
        #pragma unroll
        for(int p=0;p<2;p++)
          acc[m][p] = __builtin_amdgcn_mfma_f32_16x16x32_bf16(a[m], b[p], acc[m][p], 0,0,0);
    }
    #pragma unroll
    for(int m=0;m<2;m++)
      #pragma unroll
      for(int p=0;p<2;p++){
        const int f = (2*w+p)*16 + l16;
        float bb = b2[f];
        #pragma unroll
        for(int r=0;r<4;r++)
          sWf[(m*16+quad*4+r)*PW + f] = f16r(acc[m][p][r] + bb);
      }
  }
  __syncthreads();
  { // coalesced scatter
    for(int s=0;s<8;s++){
      int tt = w*8 + s;
      if(base + tt >= C) continue;
      int i = sI[tt], j = sJ[tt];
      float fc = sFc[tt];
      float h0 = h[(size_t)j*FD + lane];
      float h1 = h[(size_t)j*FD + lane + 64];
      float w0 = u16f(sWf[tt*PW + lane]);
      float w1 = u16f(sWf[tt*PW + lane + 64]);
      atomicAdd(&agg[(size_t)i*FD + lane],      h0*w0*fc);
      atomicAdd(&agg[(size_t)i*FD + lane + 64], h1*w1*fc);
    }
  }
}

// ---- Edge backward v6: MFMA P-phase + MFMA GEMM3, global-bf16 B-fragments ----
__global__ __launch_bounds__(256) void k_edge_bwd6(
    const float* __restrict__ h, const float* __restrict__ AB,
    const int* __restrict__ Ii, const int* __restrict__ Ij,
    const float* __restrict__ De,
    const int* __restrict__ EA, const int* __restrict__ cnt,
    const u16* __restrict__ W1t, const float* __restrict__ b1,
    const u16* __restrict__ W1b, const u16* __restrict__ W2r,
    const u16* __restrict__ W2t, const float* __restrict__ b2,
    float* __restrict__ DBe, float* __restrict__ HB){
  __shared__ u16 srbfb[TB*32];    // rbf bf16, K-padded
  __shared__ float srbf[TB*NRBF]; // rbf f32 (dbar epilogue)
  __shared__ u16 sP [TB*PW];      // P [e][c] (kept whole kernel)
  __shared__ u16 sWf[TB*PW];      // Wf -> Wbar -> tbar
  __shared__ float sdb[TB*2];     // dbar partials per n-tile
  __shared__ int sI[TB], sJ[TB], sE[TB];
  __shared__ float sFc[TB], sDd[TB], sfb[TB];
  const int tid = threadIdx.x;
  const int C = *cnt;
  const int base = blockIdx.x*TB;
  if(base >= C) return;
  if(tid < TB){
    int idx = base + tid;
    if(idx < C){
      int e = EA[idx];
      sE[tid]=e; sI[tid]=Ii[e]; sJ[tid]=Ij[e];
      float d = De[e];
      sFc[tid]=fcutf(d); sDd[tid]=d;
    } else { sE[tid]=0; sI[tid]=0; sJ[tid]=0; sFc[tid]=0.f; sDd[tid]=1.f; }
  }
  __syncthreads();
  const float step = CUTF/19.0f;
  const float coef = -0.5f/(step*step);
  for(int idx=tid; idx<TB*32; idx+=256){
    int t = idx >> 5, k = idx & 31;
    float x = sDd[t] - step*(float)k;
    if(k < NRBF){
      float v = __expf(coef*x*x);
      srbf[t*NRBF + k] = v;
      srbfb[idx] = f16r(v);
    } else srbfb[idx] = (u16)0;
  }
  __syncthreads();
  const int w = tid >> 6, lane = tid & 63;
  const int quad = lane >> 4, l16 = lane & 15;
  { // P = ssp(rbf @ W1 + b1) via MFMA (sigma recovered later from P)
    f32x4 acc[2][2];
    #pragma unroll
    for(int m=0;m<2;m++){ acc[m][0]=(f32x4){0,0,0,0}; acc[m][1]=(f32x4){0,0,0,0}; }
    bf16x8 a[2], b[2];
    #pragma unroll
    for(int m=0;m<2;m++)
      a[m] = *(const bf16x8*)&srbfb[(m*16+l16)*32 + quad*8];
    #pragma unroll
    for(int p=0;p<2;p++)
      b[p] = *(const bf16x8*)(W1t + ((2*w+p)*16+l16)*32 + quad*8);
    #pragma unroll
    for(int m=0;m<2;m++)
      #pragma unroll
      for(int p=0;p<2;p++)
        acc[m][p] = __builtin_amdgcn_mfma_f32_16x16x32_bf16(a[m], b[p], acc[m][p], 0,0,0);
    #pragma unroll
    for(int m=0;m<2;m++)
      #pragma unroll
      for(int p=0;p<2;p++){
        const int c = (2*w+p)*16 + l16;
        float bb = b1[c];
        #pragma unroll
        for(int r=0;r<4;r++)
          sP[(m*16+quad*4+r)*PW + c] = f16r(sspf(acc[m][p][r] + bb));
      }
  }
  __syncthreads();
  { // GEMM1 MFMA: Wf = P@W2 + b2; B from global W2t [f][c]
    f32x4 acc[2][2];
    #pragma unroll
    for(int m=0;m<2;m++){ acc[m][0]=(f32x4){0,0,0,0}; acc[m][1]=(f32x4){0,0,0,0}; }
    #pragma unroll
    for(int ks=0;ks<4;ks++){
      bf16x8 a[2], b[2];
      #pragma unroll
      for(int m=0;m<2;m++)
        a[m] = *(const bf16x8*)&sP[(m*16+l16)*PW + ks*32 + quad*8];
      #pragma unroll
      for(int p=0;p<2;p++)
        b[p] = *(const bf16x8*)(W2t + ((2*w+p)*16+l16)*128 + ks*32 + quad*8);
      #pragma unroll
      for(int m=0;m<2;m++)
        #pragma unroll
        for(int p=0;p<2;p++)
          acc[m][p] = __builtin_amdgcn_mfma_f32_16x16x32_bf16(a[m], b[p], acc[m][p], 0,0,0);
    }
    #pragma unroll
    for(int m=0;m<2;m++)
      #pragma unroll
      for(int p=0;p<2;p++){
        const int f = (2*w+p)*16 + l16;
        float bb = b2[f];
        #pragma unroll
        for(int r=0;r<4;r++)
          sWf[(m*16+quad*4+r)*PW + f] = f16r(acc[m][p][r] + bb);
      }
  }
  __syncthreads();
  { // scatter + Wbar (in-place per-element into sWf) + fbar
    for(int s=0;s<8;s++){
      int tt = w*8 + s;
      if(base + tt >= C) continue;
      int i = sI[tt], j = sJ[tt];
      float fc = sFc[tt];
      float a0 = AB[(size_t)i*FD + lane];
      float a1 = AB[(size_t)i*FD + lane + 64];
      float h0 = h [(size_t)j*FD + lane];
      float h1 = h [(size_t)j*FD + lane + 64];
      float w0 = u16f(sWf[tt*PW + lane]);
      float w1 = u16f(sWf[tt*PW + lane + 64]);
      atomicAdd(&HB[(size_t)j*FD + lane],      a0*w0*fc);
      atomicAdd(&HB[(size_t)j*FD + lane + 64], a1*w1*fc);
      float g0 = a0*h0, g1 = a1*h1;
      sWf[tt*PW + lane]      = f16r(g0*fc);
      sWf[tt*PW + lane + 64] = f16r(g1*fc);
      float pf = g0*w0 + g1*w1;
      #pragma unroll
      for(int d2=1; d2<64; d2<<=1) pf += __shfl_xor(pf, d2);
      if(lane == 0) sfb[tt] = pf;
    }
  }
  __syncthreads();
  float tb[2][2][4];
  { // GEMM2 MFMA: Pbar = Wbar@W2^T; B from global W2r [c][f]; sigma-trick into regs
    f32x4 acc[2][2];
    #pragma unroll
    for(int m=0;m<2;m++){ acc[m][0]=(f32x4){0,0,0,0}; acc[m][1]=(f32x4){0,0,0,0}; }
    #pragma unroll
    for(int ks=0;ks<4;ks++){
      bf16x8 a[2], b[2];
      #pragma unroll
      for(int m=0;m<2;m++)
        a[m] = *(const bf16x8*)&sWf[(m*16+l16)*PW + ks*32 + quad*8];
      #pragma unroll
      for(int p=0;p<2;p++)
        b[p] = *(const bf16x8*)(W2r + ((2*w+p)*16+l16)*128 + ks*32 + quad*8);
      #pragma unroll
      for(int m=0;m<2;m++)
        #pragma unroll
        for(int p=0;p<2;p++)
          acc[m][p] = __builtin_amdgcn_mfma_f32_16x16x32_bf16(a[m], b[p], acc[m][p], 0,0,0);
    }
    #pragma unroll
    for(int m=0;m<2;m++)
      #pragma unroll
      for(int p=0;p<2;p++){
        const int c = (2*w+p)*16 + l16;
        #pragma unroll
        for(int r=0;r<4;r++){
          float Pv = u16f(sP[(m*16+quad*4+r)*PW + c]);
          float sig = 1.0f - 0.5f*__expf(-Pv);
          tb[m][p][r] = acc[m][p][r] * sig;
        }
      }
  }
  __syncthreads();   // all Wbar fragment reads complete
  { // write tbar into sWf
    #pragma unroll
    for(int m=0;m<2;m++)
      #pragma unroll
      for(int p=0;p<2;p++){
        const int c = (2*w+p)*16 + l16;
        #pragma unroll
        for(int r=0;r<4;r++)
          sWf[(m*16+quad*4+r)*PW + c] = f16r(tb[m][p][r]);
      }
  }
  __syncthreads();
  { // GEMM3 MFMA: rbar = tbar@W1^T (B from global W1b [k32][c]); dbar partials
    const int m3 = w >> 1, p3 = w & 1;   // wave -> (m-tile, n-tile)
    f32x4 acc = (f32x4){0,0,0,0};
    #pragma unroll
    for(int ks=0;ks<4;ks++){
      bf16x8 a = *(const bf16x8*)&sWf[(m3*16+l16)*PW + ks*32 + quad*8];
      bf16x8 b = *(const bf16x8*)(W1b + (p3*16+l16)*128 + ks*32 + quad*8);
      acc = __builtin_amdgcn_mfma_f32_16x16x32_bf16(a, b, acc, 0,0,0);
    }
    const int kr = p3*16 + l16;
    float s0[4];
    #pragma unroll
    for(int r=0;r<4;r++){
      int e = m3*16 + quad*4 + r;
      float v = 0.f;
      if(kr < NRBF){
        float x = sDd[e] - step*(float)kr;
        v = acc[r] * srbf[e*NRBF + kr] * (2.f*coef*x);
      }
      s0[r] = v;
    }
    #pragma unroll
    for(int d2=1; d2<16; d2<<=1){
      #pragma unroll
      for(int r=0;r<4;r++) s0[r] += __shfl_xor(s0[r], d2);
    }
    if(l16 == 0){
      #pragma unroll
      for(int r=0;r<4;r++) sdb[(m3*16+quad*4+r)*2 + p3] = s0[r];
    }
  }
  __syncthreads();
  if(tid < TB){
    if(base + tid < C){
      const float d = sDd[tid];
      float dfc = (d < CUTF) ? (-0.5f*(PI_F/CUTF)*sinf(PI_F*d/CUTF)) : 0.f;
      DBe[sE[tid]] += sdb[tid*2+0] + sdb[tid*2+1] + sfb[tid]*dfc;
    }
  }
}

// fused atomwise head + head-backward; phase-1 loop-interchanged (R14)
__global__ __launch_bounds__(256) void k_head(const float* __restrict__ X3,
    const float* __restrict__ aW1, const float* __restrict__ ab1,
    const float* __restrict__ aW2, const float* __restrict__ ab2,
    const int* __restrict__ mol, float* __restrict__ Emol, float* __restrict__ XB, int N){
  __shared__ float sx[64*129];
  __shared__ float sg[64*65];
  const int tid = threadIdx.x;
  const int base = blockIdx.x*64;
  for(int q=0;q<8;q++){
    int ee = q*256 + tid;
    int r = ee >> 5, c = (ee & 31)*4;
    int row = base + r; if(row >= N) row = N-1;
    float4 v = *(const float4*)(X3 + (size_t)row*FD + c);
    sx[r*129 + c+0] = v.x; sx[r*129 + c+1] = v.y;
    sx[r*129 + c+2] = v.z; sx[r*129 + c+3] = v.w;
  }
  __syncthreads();
  {
    const int a = tid >> 2, q = tid & 3;
    float u[16];
    #pragma unroll
    for(int cc=0;cc<16;cc++) u[cc] = ab1[q*16 + cc];
    for(int f=0; f<128; f++){
      float xv = sx[a*129 + f];
      const float4* wp = (const float4*)(aW1 + f*64 + q*16);
      float4 w0 = wp[0], w1 = wp[1], w2 = wp[2], w3 = wp[3];
      u[0]+=xv*w0.x; u[1]+=xv*w0.y; u[2]+=xv*w0.z; u[3]+=xv*w0.w;
      u[4]+=xv*w1.x; u[5]+=xv*w1.y; u[6]+=xv*w1.z; u[7]+=xv*w1.w;
      u[8]+=xv*w2.x; u[9]+=xv*w2.y; u[10]+=xv*w2.z; u[11]+=xv*w2.w;
      u[12]+=xv*w3.x; u[13]+=xv*w3.y; u[14]+=xv*w3.z; u[15]+=xv*w3.w;
    }
    float pe = 0.f;
    #pragma unroll
    for(int cc=0;cc<16;cc++){
      int c = q*16 + cc;
      pe += sspf(u[cc])*aW2[c];
      sg[a*65 + c] = sigf(u[cc])*aW2[c];
    }
    pe += __shfl_xor(pe, 1);
    pe += __shfl_xor(pe, 2);
    if(q == 0 && base + a < N) atomicAdd(&Emol[mol[base + a]], pe + ab2[0]);
  }
  __syncthreads();
  {
    const int f = tid & 127, g2 = tid >> 7;
    float acc[32];
    #pragma unroll
    for(int q=0;q<32;q++) acc[q]=0.f;
    for(int c=0;c<64;c++){
      float w = aW1[f*64 + c];
      #pragma unroll
      for(int q=0;q<32;q++) acc[q] += sg[(g2*32+q)*65 + c]*w;
    }
    #pragma unroll
    for(int q=0;q<32;q++){
      int row = base + g2*32 + q;
      if(row < N) XB[(size_t)row*FD + f] = acc[q];
    }
  }
}

__global__ __launch_bounds__(256) void k_grad(const float* __restrict__ pos,
    const int* __restrict__ Ii, const int* __restrict__ Ij,
    const float* __restrict__ De, const float* __restrict__ DBe,
    const int* __restrict__ EA, const int* __restrict__ cnt,
    float* __restrict__ G){
  int idx = blockIdx.x*256 + threadIdx.x;
  if(idx >= *cnt) return;
  int e = EA[idx];
  float s = DBe[e] / De[e];
  int i = Ii[e], j = Ij[e];
  float dx = s*(pos[i*3+0]-pos[j*3+0]);
  float dy = s*(pos[i*3+1]-pos[j*3+1]);
  float dz = s*(pos[i*3+2]-pos[j*3+2]);
  atomicAdd(&G[i*3+0], dx); atomicAdd(&G[i*3+1], dy); atomicAdd(&G[i*3+2], dz);
  atomicAdd(&G[j*3+0], -dx); atomicAdd(&G[j*3+1], -dy); atomicAdd(&G[j*3+2], -dz);
}

__global__ __launch_bounds__(256) void k_norm(const float* __restrict__ G,
    const int* __restrict__ mol, u32* __restrict__ maxnU, int N){
  int n = blockIdx.x*256 + threadIdx.x;
  if(n >= N) return;
  float ax = G[n*3], ay = G[n*3+1], az = G[n*3+2];
  float nrm = sqrtf(ax*ax+ay*ay+az*az);
  atomicMax(&maxnU[mol[n]], __float_as_uint(nrm));
}

__global__ __launch_bounds__(256) void k_apply(const float* __restrict__ G,
    const int* __restrict__ mol, const u32* __restrict__ maxnU,
    float* __restrict__ outA, int N){
  int n = blockIdx.x*256 + threadIdx.x;
  if(n >= N) return;
  float mx = __uint_as_float(maxnU[mol[n]]);
  float coefc = fminf(1.0f/fmaxf(mx, 1e-8f), 1.0f);
  outA[n*3+0] = -G[n*3+0]*coefc;
  outA[n*3+1] = -G[n*3+1]*coefc;
  outA[n*3+2] = -G[n*3+2]*coefc;
}

extern "C" void kernel_launch(void* const* d_in, const int* in_sizes, int n_in,
                              void* d_out, int out_size, void* d_ws, size_t ws_size,
                              hipStream_t stream) {
  (void)n_in;
  const float* pos  = (const float*)d_in[0];
  const float* emb  = (const float*)d_in[1];
  const float* in2f = (const float*)d_in[2];
  const float* fW1  = (const float*)d_in[3];
  const float* fb1  = (const float*)d_in[4];
  const float* fW2  = (const float*)d_in[5];
  const float* fb2  = (const float*)d_in[6];
  const float* oW1  = (const float*)d_in[7];
  const float* ob1  = (const float*)d_in[8];
  const float* oW2  = (const float*)d_in[9];
  const float* ob2  = (const float*)d_in[10];
  const float* aW1  = (const float*)d_in[11];
  const float* ab1  = (const float*)d_in[12];
  const float* aW2  = (const float*)d_in[13];
  const float* ab2  = (const float*)d_in[14];
  const int*   Z    = (const int*)d_in[15];
  const int*   Ii   = (const int*)d_in[16];
  const int*   Ij   = (const int*)d_in[17];
  const int*   mol  = (const int*)d_in[18];
  const int N = in_sizes[15];
  const int E = in_sizes[16];
  const int M = out_size - N*3;
  const size_t NFE = (size_t)N*FD;
  float* outF = (float*)d_out;
  float* outE = outF + (size_t)N*3;
  float* ws = (float*)d_ws;
  if(ws_size < (11*NFE + 3*(size_t)E + 16 + 3*(WLSZ/2) + 64)*4) return;

  float* X0  = ws;
  float* SV0 = ws + 4*NFE;
  float* H   = ws + 7*NFE;
  float* AGG = ws + 8*NFE;
  float* XB  = ws + 9*NFE;
  float* HB  = ws + 10*NFE;
  float* De  = ws + 11*NFE;
  float* DBe = De + E;
  int*   EA  = (int*)(DBe + E);
  int*   cnt = EA + E;
  u16*   WB  = (u16*)(cnt + 16);   // 3*WLSZ u16, 16B-aligned
  float* G    = AGG;
  u32*  maxnU = (u32*)H;

  const int gN   = (int)((NFE + 255)/256);
  const int gE   = (E + 255)/256;
  const int gTF  = (E + TF-1)/TF;
  const int gTB  = (E + TB-1)/TB;
  const int gRow = (N + GR-1)/GR;
  const int gHead= (N + 63)/64;

  k_embed<<<gN,256,0,stream>>>(emb, Z, X0, (int)NFE);
  k_edge_geom<<<gE,256,0,stream>>>(pos, Ii, Ij, De, DBe, E);
  k_zero<<<1,256,0,stream>>>((float*)cnt, 1);
  k_compact<<<gE,256,0,stream>>>(De, EA, cnt, E);
  k_prep<<<(3*WLSZ+255)/256,256,0,stream>>>(fW1, fW2, WB);
  for(int l=0;l<3;l++){
    float* Xl  = X0 + (size_t)l*NFE;
    float* Xn  = X0 + (size_t)(l+1)*NFE;
    float* SVl = SV0 + (size_t)l*NFE;
    const u16* W1t = WB + l*WLSZ;
    const u16* W2t = W1t + 24576;
    k_gemm32<<<gRow,256,0,stream>>>(Xl, in2f + l*16384, nullptr, nullptr, nullptr, H, nullptr, 0, 0, N);
    k_zero<<<gN,256,0,stream>>>(AGG, (int)NFE);
    k_edge_fwd6<<<gTF,256,0,stream>>>(H, Ii, Ij, De, EA, cnt, W1t, fb1 + l*128, W2t, fb2 + l*128, AGG);
    k_gemm32<<<gRow,256,0,stream>>>(AGG, oW1 + l*16384, ob1 + l*128, nullptr, nullptr, H, SVl, 0, 1, N);
    k_gemm32<<<gRow,256,0,stream>>>(H, oW2 + l*16384, ob2 + l*128, Xl, nullptr, Xn, nullptr, 0, 0, N);
  }
  k_zero<<<(M+255)/256,256,0,stream>>>(outE, M);
  k_head<<<gHead,256,0,stream>>>(X0 + 3*NFE, aW1, ab1, aW2, ab2, mol, outE, XB, N);
  for(int l=2;l>=0;l--){
    float* Xl  = X0 + (size_t)l*NFE;
    float* SVl = SV0 + (size_t)l*NFE;
    const u16* W1t = WB + l*WLSZ;
    const u16* W1b = W1t + 4096;
    const u16* W2r = W1t + 8192;
    const u16* W2t = W1t + 24576;
    k_gemm32<<<gRow,256,0,stream>>>(XB, oW2 + l*16384, nullptr, nullptr, SVl, AGG, nullptr, 1, 0, N);
    k_gemm32<<<gRow,256,0,stream>>>(AGG, oW1 + l*16384, nullptr, nullptr, nullptr, AGG, nullptr, 1, 0, N);
    k_gemm32<<<gRow,256,0,stream>>>(Xl, in2f + l*16384, nullptr, nullptr, nullptr, H, nullptr, 0, 0, N);
    k_zero<<<gN,256,0,stream>>>(HB, (int)NFE);
    k_edge_bwd6<<<gTB,256,0,stream>>>(H, AGG, Ii, Ij, De, EA, cnt, W1t, fb1 + l*128, W1b, W2r, W2t, fb2 + l*128, DBe, HB);
    k_gemm32<<<gRow,256,0,stream>>>(HB, in2f + l*16384, nullptr, XB, nullptr, XB, nullptr, 1, 0, N);
  }
  k_zero<<<(N*3+255)/256,256,0,stream>>>(G, N*3);
  k_zero<<<(M+255)/256,256,0,stream>>>((float*)maxnU, M);
  k_grad<<<gE,256,0,stream>>>(pos, Ii, Ij, De, DBe, EA, cnt, G);
  k_norm<<<(N+255)/256,256,0,stream>>>(G, mol, maxnU, N);
  k_apply<<<(N+255)/256,256,0,stream>>>(G, mol, maxnU, outF, N);
}